// Round 4
// baseline (79.797 us; speedup 1.0000x reference)
//
#include <hip/hip_runtime.h>

// SAN subtraction2: K=7, S=1, P=3, D=1, reflect pad.
// N=8, C=64, H=W=56 -> out [8,64,49,3136] fp32.
// out[nc, kk=i*7+j, oh*56+ow] = in2[nc, refl(oh+i-3), refl(ow+j-3)] - in1[nc,oh,ow]
//
// Thread = (nc, i, oh, ow4): computes 7 j-outputs (7 float4 stores).
// R4 A/B: + bijective XCD-aware block swizzle (nwg=10976=8*1372) so all
// blocks sharing the same nc input planes run on ONE XCD's L2
// (kills ~8x cross-XCD read amplification over the fabric).

typedef float f4 __attribute__((ext_vector_type(4)));

#define KSZ 7
#define KK 49
#define HH 56
#define WW 56
#define L 3136   // 56*56
#define W4 14    // 56/4
#define NXCD 8
#define CHUNK 1372  // nwg/NXCD = 10976/8

__device__ __forceinline__ int refl56(int s) {
    // jnp reflect (no edge repeat): s<0 -> -s ; s>=56 -> 110-s
    s = s < 0 ? -s : s;
    return s >= 56 ? 110 - s : s;
}

__global__ __launch_bounds__(256) void sub2_kernel(
    const float* __restrict__ in1,
    const float* __restrict__ in2,
    float* __restrict__ out,
    int total)
{
    // XCD-aware bijective swizzle: hw round-robins consecutive blockIdx
    // across 8 XCDs; remap so each XCD owns a contiguous logical chunk
    // (64 consecutive nc-planes -> resident in that XCD's 4MB L2).
    int lb = (blockIdx.x % NXCD) * CHUNK + blockIdx.x / NXCD;

    int tid = lb * blockDim.x + threadIdx.x;
    if (tid >= total) return;

    // tid = (nc*7 + i)*784 + t,  t = oh*14 + ow4
    int t    = tid % 784;
    int rest = tid / 784;
    int i    = rest % KSZ;
    int nc   = rest / KSZ;

    int oh = t / W4;
    int ow = (t % W4) * 4;

    // query: one aligned float4 (reused 7x across i, should hit L2)
    const f4 q = *reinterpret_cast<const f4*>(in1 + (nc * HH + oh) * WW + ow);

    // key row for this i (vertical reflect picks a real row)
    int rh = refl56(oh + i - 3);
    const float* __restrict__ row = in2 + (nc * HH + rh) * WW;

    // 10-wide column window, horizontal reflect per column (branchless)
    float v[10];
#pragma unroll
    for (int d = 0; d < 10; ++d)
        v[d] = row[refl56(ow + d - 3)];

    // out base for kk = i*7 + 0
    float* outp = out + ((size_t)(nc * KK + i * KSZ) * L + oh * WW + ow);
#pragma unroll
    for (int j = 0; j < KSZ; ++j) {
        f4 r;
        r.x = v[j + 0] - q.x;
        r.y = v[j + 1] - q.y;
        r.z = v[j + 2] - q.z;
        r.w = v[j + 3] - q.w;
        *reinterpret_cast<f4*>(outp) = r;
        outp += L;
    }
}

extern "C" void kernel_launch(void* const* d_in, const int* in_sizes, int n_in,
                              void* d_out, int out_size, void* d_ws, size_t ws_size,
                              hipStream_t stream) {
    const float* in1 = (const float*)d_in[0];
    const float* in2 = (const float*)d_in[1];
    float* out = (float*)d_out;

    // threads = 512 nc * 7 i * 784 (oh,ow4) = 2,809,856 ; grid = 10976 blocks
    int total = 512 * KSZ * 784;
    int block = 256;
    int grid = (total + block - 1) / block;   // 10976, divisible by 8
    sub2_kernel<<<grid, block, 0, stream>>>(in1, in2, out, total);
}

// Round 5
// 69.915 us; speedup vs baseline: 1.1413x; 1.1413x over previous
//
#include <hip/hip_runtime.h>

// SAN subtraction2: K=7, S=1, P=3, D=1, reflect pad.
// N=8, C=64, H=W=56 -> out [8,64,49,3136] fp32.
// out[nc, kk=i*7+j, oh*56+ow] = in2[nc, refl(oh+i-3), refl(ow+j-3)] - in1[nc,oh,ow]
//
// R5: thread = (nc, oh, ow4) producing ALL 49 outputs (49 float4 stores).
// - swizzle reverted (R4 regression): default block order
// - tid decomposition + 10 column reflects amortized over 49 stores
// - q (in1) loaded once per 49 outputs
// - 49 independent 1KB/wave coalesced stores -> deep store MLP

typedef float f4 __attribute__((ext_vector_type(4)));

#define KSZ 7
#define KK 49
#define HH 56
#define WW 56
#define L 3136   // 56*56
#define W4 14    // 56/4

__device__ __forceinline__ int refl56(int s) {
    // jnp reflect (no edge repeat): s<0 -> -s ; s>=56 -> 110-s
    s = s < 0 ? -s : s;
    return s >= 56 ? 110 - s : s;
}

__global__ __launch_bounds__(256) void sub2_kernel(
    const float* __restrict__ in1,
    const float* __restrict__ in2,
    float* __restrict__ out,
    int total)
{
    int tid = blockIdx.x * blockDim.x + threadIdx.x;
    if (tid >= total) return;

    // tid = nc*784 + t,  t = oh*14 + ow4
    int t  = tid % 784;
    int nc = tid / 784;
    int oh = t / W4;
    int ow = (t % W4) * 4;

    // query pixel block: one aligned float4, used by all 49 outputs
    const f4 q = *reinterpret_cast<const f4*>(in1 + (nc * HH + oh) * WW + ow);

    // horizontal reflect indices: independent of i, hoisted
    int c[10];
#pragma unroll
    for (int d = 0; d < 10; ++d)
        c[d] = refl56(ow + d - 3);

    const float* __restrict__ plane = in2 + (size_t)nc * L;
    float* outp = out + ((size_t)nc * KK * L + oh * WW + ow);

#pragma unroll
    for (int i = 0; i < KSZ; ++i) {
        int rh = refl56(oh + i - 3);
        const float* __restrict__ row = plane + rh * WW;

        float v[10];
#pragma unroll
        for (int d = 0; d < 10; ++d)
            v[d] = row[c[d]];

#pragma unroll
        for (int j = 0; j < KSZ; ++j) {
            f4 r;
            r.x = v[j + 0] - q.x;
            r.y = v[j + 1] - q.y;
            r.z = v[j + 2] - q.z;
            r.w = v[j + 3] - q.w;
            *reinterpret_cast<f4*>(outp + (size_t)(i * KSZ + j) * L) = r;
        }
    }
}

extern "C" void kernel_launch(void* const* d_in, const int* in_sizes, int n_in,
                              void* d_out, int out_size, void* d_ws, size_t ws_size,
                              hipStream_t stream) {
    const float* in1 = (const float*)d_in[0];
    const float* in2 = (const float*)d_in[1];
    float* out = (float*)d_out;

    // threads = 512 nc * 784 (oh,ow4) = 401,408 ; grid = 1568 blocks
    int total = 512 * 784;
    int block = 256;
    int grid = (total + block - 1) / block;
    sub2_kernel<<<grid, block, 0, stream>>>(in1, in2, out, total);
}

// Round 6
// 62.760 us; speedup vs baseline: 1.2715x; 1.1140x over previous
//
#include <hip/hip_runtime.h>

// SAN subtraction2: K=7, S=1, P=3, D=1, reflect pad.
// N=8, C=64, H=W=56 -> out [8,64,49,3136] fp32.
// out[nc, kk=i*7+j, oh*56+ow] = in2[nc, refl(oh+i-3), refl(ow+j-3)] - in1[nc,oh,ow]
//
// R6: R2 structure (thread = (nc,i,oh,ow4), 7 stores), but the 10 scalar
// window loads are replaced by 3 aligned float4 loads (12-float window) +
// branchless cndmask reflect-fixups for the 2 edge lanes (ow4==0, ow4==13).
// VMEM instrs per 7 outputs: 18 -> 11 (theory: VMEM-issue-bound, not BW).

typedef float f4 __attribute__((ext_vector_type(4)));

#define KSZ 7
#define KK 49
#define HH 56
#define WW 56
#define L 3136   // 56*56
#define W4 14    // 56/4

__device__ __forceinline__ int refl56(int s) {
    s = s < 0 ? -s : s;
    return s >= 56 ? 110 - s : s;
}

__global__ __launch_bounds__(256) void sub2_kernel(
    const float* __restrict__ in1,
    const float* __restrict__ in2,
    float* __restrict__ out,
    int total)
{
    int tid = blockIdx.x * blockDim.x + threadIdx.x;
    if (tid >= total) return;

    // tid = (nc*7 + i)*784 + t,  t = oh*14 + ow4
    int t    = tid % 784;
    int rest = tid / 784;
    int i    = rest % KSZ;
    int nc   = rest / KSZ;

    int oh  = t / W4;
    int ow4 = t % W4;
    int ow  = ow4 * 4;

    // query: one aligned float4
    const f4 q = *reinterpret_cast<const f4*>(in1 + (nc * HH + oh) * WW + ow);

    // key row for this i (vertical reflect -> a real row)
    int rh = refl56(oh + i - 3);
    const float* __restrict__ row = in2 + (nc * HH + rh) * WW;

    // 12-float window, 3 aligned b128 loads at clamped base word b
    // b = clamp(4*ow4-4, 0, 44); w[e] = col (b+e)
    int b = 4 * ow4 - 4;
    b = b < 0 ? 0 : (b > 44 ? 44 : b);
    const f4 p0 = *reinterpret_cast<const f4*>(row + b);
    const f4 p1 = *reinterpret_cast<const f4*>(row + b + 4);
    const f4 p2 = *reinterpret_cast<const f4*>(row + b + 8);
    float w[12] = {p0.x, p0.y, p0.z, p0.w,
                   p1.x, p1.y, p1.z, p1.w,
                   p2.x, p2.y, p2.z, p2.w};

    // v[d] = col (4*ow4 - 4 + d); interior: v[d] = w[d].
    // Edge fixups (reflect) for ow4==0 (base clamped to 0) and ow4==13
    // (base clamped to 44). Only v1..v10 are consumed.
    bool e0  = (ow4 == 0);
    bool e13 = (ow4 == 13);
    float v1  = e0 ? w[3] : (e13 ? w[5]  : w[1]);
    float v2  = e0 ? w[2] : (e13 ? w[6]  : w[2]);
    float v3  = e0 ? w[1] : (e13 ? w[7]  : w[3]);
    float v4  = e0 ? w[0] : (e13 ? w[8]  : w[4]);
    float v5  = e0 ? w[1] : (e13 ? w[9]  : w[5]);
    float v6  = e0 ? w[2] : (e13 ? w[10] : w[6]);
    float v7  = e0 ? w[3] : (e13 ? w[11] : w[7]);
    float v8  = e0 ? w[4] : (e13 ? w[10] : w[8]);
    float v9  = e0 ? w[5] : w[9];
    float v10 = e0 ? w[6] : (e13 ? w[8]  : w[10]);
    float v[11];
    v[1]=v1; v[2]=v2; v[3]=v3; v[4]=v4; v[5]=v5;
    v[6]=v6; v[7]=v7; v[8]=v8; v[9]=v9; v[10]=v10;

    // out base for kk = i*7 + 0
    float* outp = out + ((size_t)(nc * KK + i * KSZ) * L + oh * WW + ow);
#pragma unroll
    for (int j = 0; j < KSZ; ++j) {
        f4 r;
        r.x = v[j + 1] - q.x;
        r.y = v[j + 2] - q.y;
        r.z = v[j + 3] - q.z;
        r.w = v[j + 4] - q.w;
        *reinterpret_cast<f4*>(outp) = r;
        outp += L;
    }
}

extern "C" void kernel_launch(void* const* d_in, const int* in_sizes, int n_in,
                              void* d_out, int out_size, void* d_ws, size_t ws_size,
                              hipStream_t stream) {
    const float* in1 = (const float*)d_in[0];
    const float* in2 = (const float*)d_in[1];
    float* out = (float*)d_out;

    // threads = 512 nc * 7 i * 784 (oh,ow4) = 2,809,856 ; grid = 10976
    int total = 512 * KSZ * 784;
    int block = 256;
    int grid = (total + block - 1) / block;
    sub2_kernel<<<grid, block, 0, stream>>>(in1, in2, out, total);
}